// Round 2
// baseline (551.096 us; speedup 1.0000x reference)
//
#include <hip/hip_runtime.h>
#include <hip/hip_bf16.h>

typedef __bf16 bf16_t;
typedef bf16_t bf16x8 __attribute__((ext_vector_type(8)));
typedef float  floatx4 __attribute__((ext_vector_type(4)));

#define NB    32
#define NV    207
#define NL    12
#define NROW  2484          // NV*NL rows per batch

// ---- kernel 0: transpose fp32 weights into bf16 wt: wt[mat][e][d] = W[comp][d][e]
// mats 0..3 = WQ comps, 4..7 = WK, 8..11 = WV
__global__ void transpose_w(const float* __restrict__ wq,
                            const float* __restrict__ wk,
                            const float* __restrict__ wv,
                            bf16_t* __restrict__ wt) {
  int idx = blockIdx.x * 256 + threadIdx.x;
  if (idx >= 12 * 128 * 128) return;
  int mat = idx >> 14;
  int e   = (idx >> 7) & 127;
  int d   = idx & 127;
  const float* src = (mat < 4) ? wq : ((mat < 8) ? wk : wv);
  wt[idx] = (bf16_t)src[((mat & 3) << 14) + (d << 7) + e];
}

__device__ __forceinline__ bf16x8 ldf8(const float* p) {
  floatx4 a = *(const floatx4*)p;
  floatx4 b = *(const floatx4*)(p + 4);
  bf16x8 r;
  r[0] = (bf16_t)a[0]; r[1] = (bf16_t)a[1]; r[2] = (bf16_t)a[2]; r[3] = (bf16_t)a[3];
  r[4] = (bf16_t)b[0]; r[5] = (bf16_t)b[1]; r[6] = (bf16_t)b[2]; r[7] = (bf16_t)b[3];
  return r;
}

// One wave owns 16 rows and ALL 4 components. No LDS, no barriers.
// MFMA 16x16x32: e-tile == head (dq=16). D layout: lane(quad,l16) holds
// D[e = 16h + quad*4 + r][n = l16]. Score reduce = in-lane dot(4) + shfl_xor(16,32).
//
// ROW PERMUTATION (matches reference's L-major attn vs V-major residual):
//   output memory row n gets attention from x memory row (n%NV)*NL + n/NV,
//   residual from x memory row n itself. qkvbase != outbase.
__global__ __launch_bounds__(256, 2)
void fused_attn(const float* __restrict__ x,
                const bf16_t* __restrict__ wt,
                const float* __restrict__ bq,
                const float* __restrict__ bk,
                const float* __restrict__ bv,
                const float* __restrict__ aw,
                float* __restrict__ out) {
  const int b    = blockIdx.y;
  const int wid  = threadIdx.x >> 6;
  const int lane = threadIdx.x & 63;
  const int quad = lane >> 4;
  const int l16  = lane & 15;

  const int nr = blockIdx.x * 64 + wid * 16 + l16;   // my OUTPUT row within batch b
  const bool valid = nr < NROW;
  const int n = valid ? nr : (NROW - 1);             // clamp edge (loads only)
  const int v = n % NV;
  const int l = n / NV;
  const unsigned qkvbase = (((unsigned)b * NROW + (unsigned)(v * NL + l)) << 9); // attn source row
  const unsigned outbase = (((unsigned)b * NROW + (unsigned)n) << 9);            // residual/store row

  // ---- x fragments (B operands) for all 4 components: 64 VGPR, reused 24x ----
  bf16x8 bx[4][4];
#pragma unroll
  for (int c = 0; c < 4; ++c) {
    const float* xp = x + qkvbase + (c << 7) + (quad << 3);
#pragma unroll
    for (int k = 0; k < 4; ++k) bx[c][k] = ldf8(xp + (k << 5));
  }

  // ---- per-component subset weights, hoisted out of head loop (uniform) ----
  // pw[i][s-1] = exp(aw[i][s]) / sum_{s'=1..7} exp(aw[i][s'])
  float pw[4][7];
#pragma unroll
  for (int i = 0; i < 4; ++i) {
    float s = 0.f;
#pragma unroll
    for (int t = 0; t < 7; ++t) { pw[i][t] = __expf(aw[i * 8 + 1 + t]); s += pw[i][t]; }
    const float inv = __builtin_amdgcn_rcpf(s);
#pragma unroll
    for (int t = 0; t < 7; ++t) pw[i][t] *= inv;
  }

  // ---- head loop: fully self-contained per iteration ----
  for (int h = 0; h < 8; ++h) {
    const int e0   = h << 4;
    const int wrow = ((e0 + l16) << 7) + (quad << 3);
    const int bofs = e0 + (quad << 2);

    floatx4 QQ[4], KK[4], VV[4];
#pragma unroll
    for (int c = 0; c < 4; ++c) {
      {
        const bf16_t* wb = wt + (c << 14) + wrow;
        const float*  bp = bq + (c << 7) + bofs;
        floatx4 acc; acc[0] = bp[0]; acc[1] = bp[1]; acc[2] = bp[2]; acc[3] = bp[3];
#pragma unroll
        for (int k = 0; k < 4; ++k)
          acc = __builtin_amdgcn_mfma_f32_16x16x32_bf16(*(const bf16x8*)(wb + (k << 5)), bx[c][k], acc, 0, 0, 0);
        QQ[c] = acc;
      }
      {
        const bf16_t* wb = wt + ((4 + c) << 14) + wrow;
        const float*  bp = bk + (c << 7) + bofs;
        floatx4 acc; acc[0] = bp[0]; acc[1] = bp[1]; acc[2] = bp[2]; acc[3] = bp[3];
#pragma unroll
        for (int k = 0; k < 4; ++k)
          acc = __builtin_amdgcn_mfma_f32_16x16x32_bf16(*(const bf16x8*)(wb + (k << 5)), bx[c][k], acc, 0, 0, 0);
        KK[c] = acc;
      }
      {
        const bf16_t* wb = wt + ((8 + c) << 14) + wrow;
        const float*  bp = bv + (c << 7) + bofs;
        floatx4 acc; acc[0] = bp[0]; acc[1] = bp[1]; acc[2] = bp[2]; acc[3] = bp[3];
#pragma unroll
        for (int k = 0; k < 4; ++k)
          acc = __builtin_amdgcn_mfma_f32_16x16x32_bf16(*(const bf16x8*)(wb + (k << 5)), bx[c][k], acc, 0, 0, 0);
        VV[c] = acc;
      }
    }

    // ---- scores: ee[i][j] = exp(0.25 * q_i . k_j), reduce over quads via shfl ----
    float ee[4][4];
#pragma unroll
    for (int i = 0; i < 4; ++i) {
#pragma unroll
      for (int j = 0; j < 4; ++j) {
        if (j == i) continue;
        float p = QQ[i][0] * KK[j][0];
        p += QQ[i][1] * KK[j][1];
        p += QQ[i][2] * KK[j][2];
        p += QQ[i][3] * KK[j][3];
        p += __shfl_xor(p, 16);
        p += __shfl_xor(p, 32);
        ee[i][j] = __expf(p * 0.25f);
      }
    }

    // ---- subset-softmax coefficients + PV + residual + store, per component ----
    // For comp i, others in order (a,b,c); subset s bits: 4->a, 2->b, 1->c.
    // ca = w4' + e_a*(w5'/dac + w6'/dab + w7'/dabc), w' = exp(aw)/sum_w (precomputed)
#pragma unroll
    for (int i = 0; i < 4; ++i) {
      const int ja = (i == 0) ? 1 : 0;
      const int jb = (i < 2) ? 2 : 1;
      const int jc = (i < 3) ? 3 : 2;
      const float* w = pw[i];   // w[t] = normalized weight of subset s=t+1

      const float ea = ee[i][ja], eb = ee[i][jb], ec = ee[i][jc];
      const float dab = ea + eb, dac = ea + ec, dbc = eb + ec, dabc = dab + ec;
      const float r3 = w[2] * __builtin_amdgcn_rcpf(dbc);
      const float r5 = w[4] * __builtin_amdgcn_rcpf(dac);
      const float r6 = w[5] * __builtin_amdgcn_rcpf(dab);
      const float r7 = w[6] * __builtin_amdgcn_rcpf(dabc);
      const float ca = w[3] + ea * (r5 + r6 + r7);
      const float cb = w[1] + eb * (r3 + r6 + r7);
      const float cc = w[0] + ec * (r3 + r5 + r7);

      if (valid) {
        const unsigned o = outbase + ((unsigned)i << 7) + (unsigned)bofs;
        const floatx4 res = *(const floatx4*)(x + o);
        floatx4 st;
#pragma unroll
        for (int r = 0; r < 4; ++r)
          st[r] = ca * VV[ja][r] + cb * VV[jb][r] + cc * VV[jc][r] + res[r];
        __builtin_nontemporal_store(st, (floatx4*)(out + o));
      }
    }
  }
}

extern "C" void kernel_launch(void* const* d_in, const int* in_sizes, int n_in,
                              void* d_out, int out_size, void* d_ws, size_t ws_size,
                              hipStream_t stream) {
  const float* x  = (const float*)d_in[0];
  const float* wq = (const float*)d_in[1];
  const float* bq = (const float*)d_in[2];
  const float* wk = (const float*)d_in[3];
  const float* bk = (const float*)d_in[4];
  const float* wv = (const float*)d_in[5];
  const float* bv = (const float*)d_in[6];
  const float* aw = (const float*)d_in[7];
  float* out = (float*)d_out;
  bf16_t* wt = (bf16_t*)d_ws;    // 12*128*128 bf16 = 384 KiB

  transpose_w<<<dim3(768), dim3(256), 0, stream>>>(wq, wk, wv, wt);

  // 4 waves/block, each wave = one 16-row tile, all components; 39*4*16 = 2496 >= 2484
  dim3 grid(39, NB);
  fused_attn<<<grid, dim3(256), 0, stream>>>(x, wt, bq, bk, bv, aw, out);
}

// Round 3
// 374.219 us; speedup vs baseline: 1.4727x; 1.4727x over previous
//
#include <hip/hip_runtime.h>
#include <hip/hip_bf16.h>

typedef __bf16 bf16_t;
typedef bf16_t bf16x8 __attribute__((ext_vector_type(8)));
typedef float  floatx4 __attribute__((ext_vector_type(4)));

#define NB    32
#define NV    207
#define NL    12
#define NROW  2484            // NV*NL rows per batch
#define TOTROW (NROW * NB)    // 79488
#define RPB   128             // rows per block (8 waves x 16)
#define NBLK  (TOTROW / RPB)  // 621 exactly, no tail
#define LROWE 136             // padded LDS row stride in bf16 elems (128+8) -> 272B
#define MATE  (16 * LROWE)    // 2176 elems per mat slice

// ---- kernel 0: tiled transpose fp32 W[comp][d][e] -> bf16 wt[mat][e][d] ----
// mats 0..3 = WQ comps, 4..7 = WK, 8..11 = WV. 32x32 LDS tiles, coalesced both sides.
__global__ __launch_bounds__(256)
void transpose_w(const float* __restrict__ wq,
                 const float* __restrict__ wk,
                 const float* __restrict__ wv,
                 bf16_t* __restrict__ wt) {
  __shared__ float t[32][33];
  const int mat  = blockIdx.x >> 4;          // 0..11
  const int tile = blockIdx.x & 15;          // 4x4 tiles of 32x32
  const int td = (tile >> 2) << 5;           // d-tile origin
  const int te = (tile & 3) << 5;            // e-tile origin
  const float* src = (mat < 4) ? wq : ((mat < 8) ? wk : wv);
  src += ((mat & 3) << 14);
  const int c  = threadIdx.x & 31;
  const int r0 = threadIdx.x >> 5;           // 0..7
#pragma unroll
  for (int rr = 0; rr < 4; ++rr) {
    const int r = r0 + (rr << 3);
    t[r][c] = src[((td + r) << 7) + te + c]; // read W[d][e], coalesced in e
  }
  __syncthreads();
  bf16_t* dst = wt + (mat << 14);
#pragma unroll
  for (int rr = 0; rr < 4; ++rr) {
    const int r = r0 + (rr << 3);
    dst[((te + r) << 7) + td + c] = (bf16_t)t[c][r];  // write wt[e][d], coalesced in d
  }
}

__device__ __forceinline__ bf16x8 ldf8(const float* p) {
  floatx4 a = *(const floatx4*)p;
  floatx4 b = *(const floatx4*)(p + 4);
  bf16x8 r;
  r[0] = (bf16_t)a[0]; r[1] = (bf16_t)a[1]; r[2] = (bf16_t)a[2]; r[3] = (bf16_t)a[3];
  r[4] = (bf16_t)b[0]; r[5] = (bf16_t)b[1]; r[6] = (bf16_t)b[2]; r[7] = (bf16_t)b[3];
  return r;
}

__device__ __forceinline__ float bcast(float v) {
  return __uint_as_float(__builtin_amdgcn_readfirstlane(__float_as_uint(v)));
}

// Block = 8 waves x 16 rows = 128 rows, all 4 components, all 8 heads.
// x fragments live in registers for the whole kernel (read ONCE).
// Per head h: 48 KB weight slice (12 mats x 16 e-rows) double-buffered in LDS.
// Weight global traffic: 621 blocks x 384 KB = 119 MB (was 1.9 GB).
__global__ __launch_bounds__(512, 2)
void fused_attn(const float* __restrict__ x,
                const bf16_t* __restrict__ wt,
                const float* __restrict__ bq,
                const float* __restrict__ bk,
                const float* __restrict__ bv,
                const float* __restrict__ aw,
                float* __restrict__ out) {
  __shared__ bf16_t wlds[2][12 * MATE];      // 2 x 52224 B = 104448 B

  const int tid  = threadIdx.x;
  const int wid  = tid >> 6;
  const int lane = tid & 63;
  const int quad = lane >> 4;
  const int l16  = lane & 15;

  const int g = blockIdx.x * RPB + (wid << 4) + l16;   // global output row, < 79488
  const int b = g / NROW;
  const int n = g - b * NROW;
  const int v = n % NV;
  const int l = n / NV;
  const unsigned qkvbase = (((unsigned)b * NROW + (unsigned)(v * NL + l)) << 9); // attn source row
  const unsigned outbase = ((unsigned)g << 9);                                   // residual/store row

  // ---- x fragments for all 4 components, held in regs all kernel (64 VGPR) ----
  bf16x8 bx[4][4];
#pragma unroll
  for (int c = 0; c < 4; ++c) {
    const float* xp = x + qkvbase + (c << 7) + (quad << 3);
#pragma unroll
    for (int k = 0; k < 4; ++k) bx[c][k] = ldf8(xp + (k << 5));
  }

  // ---- stage head-0 weight slice into buf0 ----
  // slot s in [0,3072): mat = s>>8, row = (s>>4)&15, ch = s&15 (16B chunks)
  bf16x8 stg[6];
#pragma unroll
  for (int q = 0; q < 6; ++q) {
    const int s = tid + (q << 9);
    stg[q] = *(const bf16x8*)(wt + ((s >> 8) << 14) + (((s >> 4) & 15) << 7) + ((s & 15) << 3));
  }
#pragma unroll
  for (int q = 0; q < 6; ++q) {
    const int s = tid + (q << 9);
    *(bf16x8*)&wlds[0][(s >> 8) * MATE + ((s >> 4) & 15) * LROWE + ((s & 15) << 3)] = stg[q];
  }

  // ---- normalized subset weights -> SGPRs (uniform) ----
  float pw[4][7];
#pragma unroll
  for (int i = 0; i < 4; ++i) {
    float sum = 0.f;
#pragma unroll
    for (int t = 0; t < 7; ++t) { pw[i][t] = __expf(aw[i * 8 + 1 + t]); sum += pw[i][t]; }
    const float inv = __builtin_amdgcn_rcpf(sum);
#pragma unroll
    for (int t = 0; t < 7; ++t) pw[i][t] = bcast(pw[i][t] * inv);
  }

  __syncthreads();

  // ---- head loop ----
  for (int h = 0; h < 8; ++h) {
    // issue next head's staging loads early (hidden under compute)
    if (h < 7) {
#pragma unroll
      for (int q = 0; q < 6; ++q) {
        const int s = tid + (q << 9);
        stg[q] = *(const bf16x8*)(wt + ((s >> 8) << 14) + ((((h + 1) << 4) + ((s >> 4) & 15)) << 7) + ((s & 15) << 3));
      }
    }

    const int bofs = (h << 4) + (quad << 2);
    const bf16_t* lb = &wlds[h & 1][l16 * LROWE + (quad << 3)];

    floatx4 QQ[4], KK[4], VV[4];
#pragma unroll
    for (int c = 0; c < 4; ++c) {
      {
        const bf16_t* wb = lb + c * MATE;
        const float*  bp = bq + (c << 7) + bofs;
        floatx4 acc; acc[0] = bp[0]; acc[1] = bp[1]; acc[2] = bp[2]; acc[3] = bp[3];
#pragma unroll
        for (int k = 0; k < 4; ++k)
          acc = __builtin_amdgcn_mfma_f32_16x16x32_bf16(*(const bf16x8*)(wb + (k << 5)), bx[c][k], acc, 0, 0, 0);
        QQ[c] = acc;
      }
      {
        const bf16_t* wb = lb + (4 + c) * MATE;
        const float*  bp = bk + (c << 7) + bofs;
        floatx4 acc; acc[0] = bp[0]; acc[1] = bp[1]; acc[2] = bp[2]; acc[3] = bp[3];
#pragma unroll
        for (int k = 0; k < 4; ++k)
          acc = __builtin_amdgcn_mfma_f32_16x16x32_bf16(*(const bf16x8*)(wb + (k << 5)), bx[c][k], acc, 0, 0, 0);
        KK[c] = acc;
      }
      {
        const bf16_t* wb = lb + (8 + c) * MATE;
        const float*  bp = bv + (c << 7) + bofs;
        floatx4 acc; acc[0] = bp[0]; acc[1] = bp[1]; acc[2] = bp[2]; acc[3] = bp[3];
#pragma unroll
        for (int k = 0; k < 4; ++k)
          acc = __builtin_amdgcn_mfma_f32_16x16x32_bf16(*(const bf16x8*)(wb + (k << 5)), bx[c][k], acc, 0, 0, 0);
        VV[c] = acc;
      }
    }

    // ---- scores: ee[i][j] = exp(0.25 * q_i . k_j) ----
    float ee[4][4];
#pragma unroll
    for (int i = 0; i < 4; ++i) {
#pragma unroll
      for (int j = 0; j < 4; ++j) {
        if (j == i) continue;
        float p = QQ[i][0] * KK[j][0];
        p += QQ[i][1] * KK[j][1];
        p += QQ[i][2] * KK[j][2];
        p += QQ[i][3] * KK[j][3];
        p += __shfl_xor(p, 16);
        p += __shfl_xor(p, 32);
        ee[i][j] = __expf(p * 0.25f);
      }
    }

    // ---- subset-softmax coefficients + PV + residual + store ----
#pragma unroll
    for (int i = 0; i < 4; ++i) {
      const int ja = (i == 0) ? 1 : 0;
      const int jb = (i < 2) ? 2 : 1;
      const int jc = (i < 3) ? 3 : 2;
      const float* w = pw[i];

      const float ea = ee[i][ja], eb = ee[i][jb], ec = ee[i][jc];
      const float dab = ea + eb, dac = ea + ec, dbc = eb + ec, dabc = dab + ec;
      const float r3 = w[2] * __builtin_amdgcn_rcpf(dbc);
      const float r5 = w[4] * __builtin_amdgcn_rcpf(dac);
      const float r6 = w[5] * __builtin_amdgcn_rcpf(dab);
      const float r7 = w[6] * __builtin_amdgcn_rcpf(dabc);
      const float ca = w[3] + ea * (r5 + r6 + r7);
      const float cb = w[1] + eb * (r3 + r6 + r7);
      const float cc = w[0] + ec * (r3 + r5 + r7);

      const unsigned o = outbase + ((unsigned)i << 7) + (unsigned)bofs;
      const floatx4 res = *(const floatx4*)(x + o);
      floatx4 st;
#pragma unroll
      for (int r = 0; r < 4; ++r)
        st[r] = ca * VV[ja][r] + cb * VV[jb][r] + cc * VV[jc][r] + res[r];
      __builtin_nontemporal_store(st, (floatx4*)(out + o));
    }

    // ---- write next head's slice, flip buffers ----
    if (h < 7) {
#pragma unroll
      for (int q = 0; q < 6; ++q) {
        const int s = tid + (q << 9);
        *(bf16x8*)&wlds[(h + 1) & 1][(s >> 8) * MATE + ((s >> 4) & 15) * LROWE + ((s & 15) << 3)] = stg[q];
      }
      __syncthreads();
    }
  }
}

extern "C" void kernel_launch(void* const* d_in, const int* in_sizes, int n_in,
                              void* d_out, int out_size, void* d_ws, size_t ws_size,
                              hipStream_t stream) {
  const float* x  = (const float*)d_in[0];
  const float* wq = (const float*)d_in[1];
  const float* bq = (const float*)d_in[2];
  const float* wk = (const float*)d_in[3];
  const float* bk = (const float*)d_in[4];
  const float* wv = (const float*)d_in[5];
  const float* bv = (const float*)d_in[6];
  const float* aw = (const float*)d_in[7];
  float* out = (float*)d_out;
  bf16_t* wt = (bf16_t*)d_ws;    // 12*128*128 bf16 = 384 KiB

  transpose_w<<<dim3(192), dim3(256), 0, stream>>>(wq, wk, wv, wt);

  fused_attn<<<dim3(NBLK), dim3(512), 0, stream>>>(x, wt, bq, bk, bv, aw, out);
}